// Round 1
// baseline (84.414 us; speedup 1.0000x reference)
//
#include <hip/hip_runtime.h>

// D-FINE post-processor: per-batch top-K over sigmoid(logits) flattened [Q*C],
// labels = idx % C, boxes gathered at idx / C, decoded cxcywh->xyxy * [s0,s1,s0,s1].
// Output (all float32): labels [B*K] | boxes [B*K*4] | scores [B*K]

constexpr int NTHREADS = 1024;
constexpr int NBINS    = 4096;   // top 12 bits of sortable key
constexpr int CAP      = 4096;   // candidate capacity (power of 2)

__device__ __forceinline__ unsigned f2key(float f) {
    unsigned u = __float_as_uint(f);
    // negative floats -> flipped (descend below positives), positives -> set top bit
    return (u & 0x80000000u) ? ~u : (u | 0x80000000u);
}
__device__ __forceinline__ float key2f(unsigned k) {
    unsigned u = (k & 0x80000000u) ? (k & 0x7FFFFFFFu) : ~k;
    return __uint_as_float(u);
}

__global__ __launch_bounds__(NTHREADS) void dfine_topk_kernel(
    const float* __restrict__ logits,   // [B, Q*C]
    const float* __restrict__ pboxes,   // [B, Q, 4]  (cx, cy, w, h)
    const float* __restrict__ sizes,    // [B, 2]
    float* __restrict__ out,            // labels | boxes | scores
    int B, int Q, int C, int K)
{
    const int b   = blockIdx.x;
    const int tid = threadIdx.x;
    const int N   = Q * C;
    const float* lg = logits + (long long)b * N;

    __shared__ unsigned hist[NBINS];
    __shared__ unsigned long long cand[CAP];
    __shared__ unsigned scanbuf[NTHREADS];
    __shared__ unsigned candCount;
    __shared__ unsigned threshBin;

    for (int i = tid; i < NBINS; i += NTHREADS) hist[i] = 0u;
    if (tid == 0) { candCount = 0u; threshBin = 0u; }
    __syncthreads();

    // ---- Pass A: histogram of top 12 bits of sortable key ----
    for (int i = tid; i < N; i += NTHREADS) {
        unsigned key = f2key(lg[i]);
        atomicAdd(&hist[key >> 20], 1u);
    }
    __syncthreads();

    // ---- Suffix scan (from highest bin down) to find threshold bin ----
    unsigned carry = 0u;
    for (int chunk = 0; chunk < NBINS / NTHREADS; ++chunk) {
        int bin = NBINS - 1 - (chunk * NTHREADS + tid);
        unsigned v = hist[bin];
        scanbuf[tid] = v;
        __syncthreads();
        // Hillis-Steele inclusive scan over tid
        for (int off = 1; off < NTHREADS; off <<= 1) {
            unsigned t = (tid >= off) ? scanbuf[tid - off] : 0u;
            __syncthreads();
            scanbuf[tid] += t;
            __syncthreads();
        }
        unsigned incl  = scanbuf[tid];
        unsigned total = scanbuf[NTHREADS - 1];
        unsigned cum   = carry + incl;
        if (v > 0u && (cum - v) < (unsigned)K && cum >= (unsigned)K) {
            threshBin = (unsigned)bin;   // bin where cumulative-from-top crosses K
        }
        carry += total;
        __syncthreads();
    }

    // ---- Pass B: gather candidates with bin >= threshold bin ----
    const unsigned tb = threshBin;
    for (int i = tid; i < N; i += NTHREADS) {
        unsigned key = f2key(lg[i]);
        if ((key >> 20) >= tb) {
            unsigned pos = atomicAdd(&candCount, 1u);
            if (pos < (unsigned)CAP) {
                // pack: high 32 = key (desc), low 32 = ~idx (so equal keys sort idx-ascending)
                cand[pos] = ((unsigned long long)key << 32)
                          | (unsigned long long)(0xFFFFFFFFu - (unsigned)i);
            }
        }
    }
    __syncthreads();

    int n = (int)min(candCount, (unsigned)CAP);
    int P = 2;
    while (P < n) P <<= 1;
    for (int i = n + tid; i < P; i += NTHREADS) cand[i] = 0ull;  // padding sinks to bottom
    __syncthreads();

    // ---- Bitonic sort, descending on packed 64-bit key ----
    for (int ksz = 2; ksz <= P; ksz <<= 1) {
        for (int j = ksz >> 1; j > 0; j >>= 1) {
            for (int i = tid; i < P; i += NTHREADS) {
                int ixj = i ^ j;
                if (ixj > i) {
                    unsigned long long a = cand[i];
                    unsigned long long c = cand[ixj];
                    bool upper = ((i & ksz) == 0);
                    if (upper ? (a < c) : (a > c)) { cand[i] = c; cand[ixj] = a; }
                }
            }
            __syncthreads();
        }
    }

    // ---- Emit top-K ----
    const int BK = B * K;
    float* __restrict__ out_labels = out;
    float* __restrict__ out_boxes  = out + BK;
    float* __restrict__ out_scores = out + (long long)BK * 5;
    const float s0 = sizes[2 * b];
    const float s1 = sizes[2 * b + 1];

    for (int k = tid; k < K; k += NTHREADS) {
        unsigned long long v = cand[k];
        unsigned key = (unsigned)(v >> 32);
        unsigned idx = 0xFFFFFFFFu - (unsigned)(v & 0xFFFFFFFFull);
        float logit = key2f(key);
        float score = 1.0f / (1.0f + expf(-logit));
        int label = (int)(idx % (unsigned)C);
        int q     = (int)(idx / (unsigned)C);
        const float* bp = pboxes + ((long long)b * Q + q) * 4;
        float cx = bp[0], cy = bp[1], w = bp[2], h = bp[3];
        int o = b * K + k;
        out_labels[o] = (float)label;
        out_scores[o] = score;
        float4 bb = make_float4((cx - 0.5f * w) * s0,
                                (cy - 0.5f * h) * s1,
                                (cx + 0.5f * w) * s0,
                                (cy + 0.5f * h) * s1);
        *reinterpret_cast<float4*>(out_boxes + 4LL * o) = bb;
    }
}

extern "C" void kernel_launch(void* const* d_in, const int* in_sizes, int n_in,
                              void* d_out, int out_size, void* d_ws, size_t ws_size,
                              hipStream_t stream) {
    const float* logits = (const float*)d_in[0];
    const float* pboxes = (const float*)d_in[1];
    const float* sizes  = (const float*)d_in[2];
    // d_in[3] = num_top_queries (device scalar) — value derived from out_size instead.

    const int B = in_sizes[2] / 2;                 // 256
    const int Q = in_sizes[1] / (4 * B);           // 1000
    const int C = in_sizes[0] / (B * Q);           // 80
    const int K = out_size / (6 * B);              // 300

    dfine_topk_kernel<<<B, NTHREADS, 0, stream>>>(
        logits, pboxes, sizes, (float*)d_out, B, Q, C, K);
}

// Round 2
// 83.139 us; speedup vs baseline: 1.0153x; 1.0153x over previous
//
#include <hip/hip_runtime.h>

// D-FINE post-processor, single-pass:
//  - 256 blocks (1 per batch) x 512 threads
//  - whole batch (80000 logits) register-cached as sortable keys (40 x uint4/thread)
//  - 4096-bin LDS histogram -> hierarchical wave-scan threshold find (2 barriers)
//  - candidate gather from registers -> rank-based selection (no bitonic sort)
// Output (float32): labels [B*K] | boxes [B*K*4] | scores [B*K]

constexpr int NT    = 512;
constexpr int ITERS = 40;     // supports N <= NT*ITERS*4 = 81920  (actual N = 80000)
constexpr int NBINS = 4096;   // top 12 bits of sortable key
constexpr int CAP   = 4096;   // candidate capacity

__device__ __forceinline__ unsigned f2key(float f) {
    unsigned u = __float_as_uint(f);
    return (u & 0x80000000u) ? ~u : (u | 0x80000000u);
}
__device__ __forceinline__ float key2f(unsigned k) {
    unsigned u = (k & 0x80000000u) ? (k & 0x7FFFFFFFu) : ~k;
    return __uint_as_float(u);
}

__global__ __launch_bounds__(NT, 2) void dfine_topk_kernel(
    const float* __restrict__ logits,   // [B, Q*C]
    const float* __restrict__ pboxes,   // [B, Q, 4]  (cx, cy, w, h)
    const float* __restrict__ sizes,    // [B, 2]
    float* __restrict__ out,            // labels | boxes | scores
    int B, int Q, int C, int K)
{
    const int b   = blockIdx.x;
    const int tid = threadIdx.x;
    const int N   = Q * C;
    const int N4  = N >> 2;             // N divisible by 4 (C=80)
    const float4* lg4 = reinterpret_cast<const float4*>(logits + (long long)b * N);

    __shared__ unsigned hist[NBINS];
    __shared__ unsigned long long cand[CAP];
    __shared__ unsigned partial[NT];
    __shared__ unsigned candCount;
    __shared__ unsigned threshBin;

    for (int i = tid; i < NBINS; i += NT) hist[i] = 0u;
    if (tid == 0) candCount = 0u;
    __syncthreads();

    // ---- single global pass: burst-load whole batch into registers as keys ----
    uint4 keys[ITERS];
    #pragma unroll
    for (int it = 0; it < ITERS; ++it) {
        int i4 = it * NT + tid;
        if (i4 < N4) {
            float4 v = lg4[i4];
            keys[it].x = f2key(v.x);
            keys[it].y = f2key(v.y);
            keys[it].z = f2key(v.z);
            keys[it].w = f2key(v.w);
        } else {
            keys[it].x = keys[it].y = keys[it].z = keys[it].w = 0u;
        }
    }

    // ---- histogram of top 12 key bits (LDS atomics) ----
    #pragma unroll
    for (int it = 0; it < ITERS; ++it) {
        if (it * NT + tid < N4) {
            atomicAdd(&hist[keys[it].x >> 20], 1u);
            atomicAdd(&hist[keys[it].y >> 20], 1u);
            atomicAdd(&hist[keys[it].z >> 20], 1u);
            atomicAdd(&hist[keys[it].w >> 20], 1u);
        }
    }
    __syncthreads();

    // ---- hierarchical threshold find (2 barriers total) ----
    {
        const int BPT = NBINS / NT;                 // 8 bins per thread
        unsigned s = 0;
        #pragma unroll
        for (int m = 0; m < BPT; ++m) s += hist[tid * BPT + m];
        partial[tid] = s;
    }
    __syncthreads();
    if (tid < 64) {
        const int PPG = NT / 64;                    // 8 partials per lane
        unsigned gs = 0;
        #pragma unroll
        for (int m = 0; m < PPG; ++m) gs += partial[tid * PPG + m];
        // gs = count of bins [tid*64, (tid+1)*64)
        unsigned pre = gs;                          // inclusive prefix over lanes
        #pragma unroll
        for (int off = 1; off < 64; off <<= 1) {
            unsigned t = __shfl_up(pre, off);
            if (tid >= off) pre += t;
        }
        unsigned total = __shfl(pre, 63);
        unsigned suf   = total - (pre - gs);        // suffix incl. self
        unsigned long long m1 = __ballot(suf >= (unsigned)K);
        int g = 63 - __clzll(m1);                   // crossing group (highest lane with suf>=K)
        unsigned above = total - __shfl(pre, g);    // count in groups above g
        // scan the 64 bins of group g in-wave
        unsigned hv = hist[g * 64 + tid];
        unsigned pre2 = hv;
        #pragma unroll
        for (int off = 1; off < 64; off <<= 1) {
            unsigned t = __shfl_up(pre2, off);
            if (tid >= off) pre2 += t;
        }
        unsigned total2 = __shfl(pre2, 63);
        unsigned suf2   = above + total2 - (pre2 - hv);
        unsigned long long m2 = __ballot(suf2 >= (unsigned)K);
        int l2 = 63 - __clzll(m2);
        if (tid == 0) threshBin = (unsigned)(g * 64 + l2);
    }
    __syncthreads();
    const unsigned tb = threshBin;

    // ---- gather candidates from register cache ----
    #pragma unroll
    for (int it = 0; it < ITERS; ++it) {
        int i4 = it * NT + tid;
        if (i4 < N4) {
            unsigned k0 = keys[it].x, k1 = keys[it].y, k2 = keys[it].z, k3 = keys[it].w;
            if ((k0 >> 20) >= tb) { unsigned p = atomicAdd(&candCount, 1u);
                if (p < (unsigned)CAP) cand[p] = ((unsigned long long)k0 << 32) | (unsigned long long)(0xFFFFFFFFu - (unsigned)(4*i4 + 0)); }
            if ((k1 >> 20) >= tb) { unsigned p = atomicAdd(&candCount, 1u);
                if (p < (unsigned)CAP) cand[p] = ((unsigned long long)k1 << 32) | (unsigned long long)(0xFFFFFFFFu - (unsigned)(4*i4 + 1)); }
            if ((k2 >> 20) >= tb) { unsigned p = atomicAdd(&candCount, 1u);
                if (p < (unsigned)CAP) cand[p] = ((unsigned long long)k2 << 32) | (unsigned long long)(0xFFFFFFFFu - (unsigned)(4*i4 + 2)); }
            if ((k3 >> 20) >= tb) { unsigned p = atomicAdd(&candCount, 1u);
                if (p < (unsigned)CAP) cand[p] = ((unsigned long long)k3 << 32) | (unsigned long long)(0xFFFFFFFFu - (unsigned)(4*i4 + 3)); }
        }
    }
    __syncthreads();

    const int n = (int)min(candCount, (unsigned)CAP);   // n >= K guaranteed

    // ---- rank-based selection + emit (broadcast LDS reads, no sort) ----
    const int BK = B * K;
    float* __restrict__ out_labels = out;
    float* __restrict__ out_boxes  = out + BK;
    float* __restrict__ out_scores = out + (long long)BK * 5;
    const float s0 = sizes[2 * b];
    const float s1 = sizes[2 * b + 1];

    for (int t = tid; t < n; t += NT) {
        unsigned long long my = cand[t];
        int r = 0;
        for (int j = 0; j < n; ++j) r += (cand[j] > my);   // keys unique (idx packed)
        if (r < K) {
            unsigned key = (unsigned)(my >> 32);
            unsigned idx = 0xFFFFFFFFu - (unsigned)(my & 0xFFFFFFFFull);
            float logit = key2f(key);
            float score = 1.0f / (1.0f + expf(-logit));
            int label = (int)(idx % (unsigned)C);
            int q     = (int)(idx / (unsigned)C);
            float4 bp = *reinterpret_cast<const float4*>(pboxes + ((long long)b * Q + q) * 4);
            int o = b * K + r;
            out_labels[o] = (float)label;
            out_scores[o] = score;
            float4 bb;
            bb.x = (bp.x - 0.5f * bp.z) * s0;
            bb.y = (bp.y - 0.5f * bp.w) * s1;
            bb.z = (bp.x + 0.5f * bp.z) * s0;
            bb.w = (bp.y + 0.5f * bp.w) * s1;
            *reinterpret_cast<float4*>(out_boxes + 4LL * o) = bb;
        }
    }
}

extern "C" void kernel_launch(void* const* d_in, const int* in_sizes, int n_in,
                              void* d_out, int out_size, void* d_ws, size_t ws_size,
                              hipStream_t stream) {
    const float* logits = (const float*)d_in[0];
    const float* pboxes = (const float*)d_in[1];
    const float* sizes  = (const float*)d_in[2];

    const int B = in_sizes[2] / 2;                 // 256
    const int Q = in_sizes[1] / (4 * B);           // 1000
    const int C = in_sizes[0] / (B * Q);           // 80
    const int K = out_size / (6 * B);              // 300

    dfine_topk_kernel<<<B, NT, 0, stream>>>(
        logits, pboxes, sizes, (float*)d_out, B, Q, C, K);
}

// Round 3
// 43.449 us; speedup vs baseline: 1.9428x; 1.9135x over previous
//
#include <hip/hip_runtime.h>

// D-FINE post-processor: per-batch top-K over sigmoid(logits) flattened [Q*C].
// One block per batch, 1024 threads, two MLP-batched passes over logits:
//   pass A: 4096-bin histogram of top-12 sortable-key bits (8x float4 bursts)
//   threshold find: 2-barrier hierarchical wave scan
//   pass B: gather candidates >= threshold bin (L3-served re-read)
//   rank-based selection (count-greater), direct scatter to output rank
// Output (float32): labels [B*K] | boxes [B*K*4] | scores [B*K]

constexpr int NT    = 1024;
constexpr int UN    = 8;      // float4 loads in flight per thread per super-iter
constexpr int NBINS = 4096;
constexpr int CAP   = 4096;

__device__ __forceinline__ unsigned f2key(float f) {
    unsigned u = __float_as_uint(f);
    return (u & 0x80000000u) ? ~u : (u | 0x80000000u);
}
__device__ __forceinline__ float key2f(unsigned k) {
    unsigned u = (k & 0x80000000u) ? (k & 0x7FFFFFFFu) : ~k;
    return __uint_as_float(u);
}

__global__ __launch_bounds__(NT) void dfine_topk_kernel(
    const float* __restrict__ logits,   // [B, Q*C]
    const float* __restrict__ pboxes,   // [B, Q, 4]  (cx, cy, w, h)
    const float* __restrict__ sizes,    // [B, 2]
    float* __restrict__ out,            // labels | boxes | scores
    int B, int Q, int C, int K)
{
    const int b   = blockIdx.x;
    const int tid = threadIdx.x;
    const int N   = Q * C;
    const int N4  = N >> 2;             // N divisible by 4 (C=80)
    const float4* __restrict__ lg4 = reinterpret_cast<const float4*>(logits + (long long)b * N);

    __shared__ unsigned hist[NBINS];
    __shared__ unsigned long long cand[CAP];
    __shared__ unsigned partial[NT];
    __shared__ unsigned candCount;
    __shared__ unsigned threshBin;

    for (int i = tid; i < NBINS; i += NT) hist[i] = 0u;
    if (tid == 0) candCount = 0u;
    __syncthreads();

    // ---- Pass A: histogram, 8 b128 loads in flight before any LDS atomic ----
    for (int s = 0; s < N4; s += UN * NT) {
        uint4 kk[UN];
        #pragma unroll
        for (int j = 0; j < UN; ++j) {
            int i4 = s + j * NT + tid;
            int c  = (i4 < N4) ? i4 : (N4 - 1);      // clamped load, predicated use
            float4 v = lg4[c];
            kk[j].x = f2key(v.x); kk[j].y = f2key(v.y);
            kk[j].z = f2key(v.z); kk[j].w = f2key(v.w);
        }
        #pragma unroll
        for (int j = 0; j < UN; ++j) {
            int i4 = s + j * NT + tid;
            if (i4 < N4) {
                atomicAdd(&hist[kk[j].x >> 20], 1u);
                atomicAdd(&hist[kk[j].y >> 20], 1u);
                atomicAdd(&hist[kk[j].z >> 20], 1u);
                atomicAdd(&hist[kk[j].w >> 20], 1u);
            }
        }
    }
    __syncthreads();

    // ---- Hierarchical threshold find (2 barriers) ----
    {
        const int BPT = NBINS / NT;                  // 4 bins/thread
        unsigned s = 0;
        #pragma unroll
        for (int m = 0; m < BPT; ++m) s += hist[tid * BPT + m];
        partial[tid] = s;
    }
    __syncthreads();
    if (tid < 64) {
        const int PPG = NT / 64;                     // 16 partials/lane
        unsigned gs = 0;
        #pragma unroll
        for (int m = 0; m < PPG; ++m) gs += partial[tid * PPG + m];
        unsigned pre = gs;                           // inclusive prefix over lanes
        #pragma unroll
        for (int off = 1; off < 64; off <<= 1) {
            unsigned t = __shfl_up(pre, off);
            if (tid >= off) pre += t;
        }
        unsigned total = __shfl(pre, 63);
        unsigned suf   = total - (pre - gs);         // suffix incl. self
        unsigned long long m1 = __ballot(suf >= (unsigned)K);
        int g = 63 - __clzll(m1);                    // highest group with suffix >= K
        unsigned above = total - __shfl(pre, g);
        const int BPL = NBINS / 64 / 64;             // bins per lane within group = 1
        (void)BPL;
        unsigned hv = hist[g * 64 + tid];
        unsigned pre2 = hv;
        #pragma unroll
        for (int off = 1; off < 64; off <<= 1) {
            unsigned t = __shfl_up(pre2, off);
            if (tid >= off) pre2 += t;
        }
        unsigned total2 = __shfl(pre2, 63);
        unsigned suf2   = above + total2 - (pre2 - hv);
        unsigned long long m2 = __ballot(suf2 >= (unsigned)K);
        int l2 = 63 - __clzll(m2);
        if (tid == 0) threshBin = (unsigned)(g * 64 + l2);
    }
    __syncthreads();
    const unsigned tb = threshBin;

    // ---- Pass B: gather candidates (re-read is L3-resident), same MLP batching ----
    for (int s = 0; s < N4; s += UN * NT) {
        uint4 kk[UN];
        #pragma unroll
        for (int j = 0; j < UN; ++j) {
            int i4 = s + j * NT + tid;
            int c  = (i4 < N4) ? i4 : (N4 - 1);
            float4 v = lg4[c];
            kk[j].x = f2key(v.x); kk[j].y = f2key(v.y);
            kk[j].z = f2key(v.z); kk[j].w = f2key(v.w);
        }
        #pragma unroll
        for (int j = 0; j < UN; ++j) {
            int i4 = s + j * NT + tid;
            if (i4 < N4) {
                unsigned base = (unsigned)(4 * i4);
                unsigned k0 = kk[j].x, k1 = kk[j].y, k2 = kk[j].z, k3 = kk[j].w;
                if ((k0 >> 20) >= tb) { unsigned p = atomicAdd(&candCount, 1u);
                    if (p < (unsigned)CAP) cand[p] = ((unsigned long long)k0 << 32) | (unsigned long long)(0xFFFFFFFFu - (base + 0)); }
                if ((k1 >> 20) >= tb) { unsigned p = atomicAdd(&candCount, 1u);
                    if (p < (unsigned)CAP) cand[p] = ((unsigned long long)k1 << 32) | (unsigned long long)(0xFFFFFFFFu - (base + 1)); }
                if ((k2 >> 20) >= tb) { unsigned p = atomicAdd(&candCount, 1u);
                    if (p < (unsigned)CAP) cand[p] = ((unsigned long long)k2 << 32) | (unsigned long long)(0xFFFFFFFFu - (base + 2)); }
                if ((k3 >> 20) >= tb) { unsigned p = atomicAdd(&candCount, 1u);
                    if (p < (unsigned)CAP) cand[p] = ((unsigned long long)k3 << 32) | (unsigned long long)(0xFFFFFFFFu - (base + 3)); }
            }
        }
    }
    __syncthreads();

    const int n = (int)min(candCount, (unsigned)CAP);   // n >= K by construction

    // ---- Rank-based selection + emit ----
    const int BK = B * K;
    float* __restrict__ out_labels = out;
    float* __restrict__ out_boxes  = out + BK;
    float* __restrict__ out_scores = out + (long long)BK * 5;
    const float s0 = sizes[2 * b];
    const float s1 = sizes[2 * b + 1];

    for (int t = tid; t < n; t += NT) {
        unsigned long long my = cand[t];
        int r = 0;
        for (int j = 0; j < n; ++j) r += (cand[j] > my);   // packed keys are unique
        if (r < K) {
            unsigned key = (unsigned)(my >> 32);
            unsigned idx = 0xFFFFFFFFu - (unsigned)(my & 0xFFFFFFFFull);
            float logit = key2f(key);
            float score = 1.0f / (1.0f + expf(-logit));
            int label = (int)(idx % (unsigned)C);
            int q     = (int)(idx / (unsigned)C);
            float4 bp = *reinterpret_cast<const float4*>(pboxes + ((long long)b * Q + q) * 4);
            int o = b * K + r;
            out_labels[o] = (float)label;
            out_scores[o] = score;
            float4 bb;
            bb.x = (bp.x - 0.5f * bp.z) * s0;
            bb.y = (bp.y - 0.5f * bp.w) * s1;
            bb.z = (bp.x + 0.5f * bp.z) * s0;
            bb.w = (bp.y + 0.5f * bp.w) * s1;
            *reinterpret_cast<float4*>(out_boxes + 4LL * o) = bb;
        }
    }
}

extern "C" void kernel_launch(void* const* d_in, const int* in_sizes, int n_in,
                              void* d_out, int out_size, void* d_ws, size_t ws_size,
                              hipStream_t stream) {
    const float* logits = (const float*)d_in[0];
    const float* pboxes = (const float*)d_in[1];
    const float* sizes  = (const float*)d_in[2];

    const int B = in_sizes[2] / 2;                 // 256
    const int Q = in_sizes[1] / (4 * B);           // 1000
    const int C = in_sizes[0] / (B * Q);           // 80
    const int K = out_size / (6 * B);              // 300

    dfine_topk_kernel<<<B, NT, 0, stream>>>(
        logits, pboxes, sizes, (float*)d_out, B, Q, C, K);
}